// Round 1
// baseline (674.154 us; speedup 1.0000x reference)
//
#include <hip/hip_runtime.h>
#include <math.h>

#define BB 2
#define CC 192
#define SS 512
#define BW 21
#define HALF 10
#define KS 7

// Kernel 1: band mean over vertical 21-window at the diagonal column, then
// depthwise conv1d k=7 (cross-correlation, zero pad 3). One block per (b,c).
__global__ __launch_bounds__(SS) void band_conv_kernel(
    const float* __restrict__ x, const float* __restrict__ conv_w,
    float* __restrict__ attn1) {
  const int bc = blockIdx.x;            // b*CC + c
  const int c  = bc % CC;
  const int j  = threadIdx.x;           // column / diag position, 0..511
  const float* xs = x + (size_t)bc * SS * SS;

  float sum = 0.f;
#pragma unroll
  for (int k = 0; k < BW; ++k) {
    int r = j + k - HALF;
    if (r >= 0 && r < SS) sum += xs[(size_t)r * SS + j];
  }

  __shared__ float sband[SS];
  sband[j] = sum * (1.0f / (float)BW);
  __syncthreads();

  float w[KS];
#pragma unroll
  for (int t = 0; t < KS; ++t) w[t] = conv_w[c * KS + t];

  float acc = 0.f;
#pragma unroll
  for (int t = 0; t < KS; ++t) {
    int s = j + t - (KS / 2);
    if (s >= 0 && s < SS) acc += sband[s] * w[t];
  }
  attn1[(size_t)bc * SS + j] = acc;
}

// Kernel 2: pointwise [C x C] mix + bias, then softmax over s per (b,d).
// One block per (b,d), 512 threads = 8 waves.
__global__ __launch_bounds__(SS) void point_softmax_kernel(
    const float* __restrict__ attn1, const float* __restrict__ point_w,
    const float* __restrict__ point_b, float* __restrict__ attn2) {
  const int bd = blockIdx.x;            // b*CC + d
  const int b  = bd / CC;
  const int d  = bd % CC;
  const int s  = threadIdx.x;

  const float* a1 = attn1 + (size_t)b * CC * SS;
  const float* pw = point_w + (size_t)d * CC;   // block-uniform -> s_loads

  float acc = point_b[d];
#pragma unroll 4
  for (int c = 0; c < CC; ++c) acc += pw[c] * a1[(size_t)c * SS + s];

  // block softmax over the 512 s-values
  const int wave = s >> 6, lane = s & 63;
  __shared__ float redm[8];
  __shared__ float reds[8];

  float m = acc;
#pragma unroll
  for (int off = 32; off >= 1; off >>= 1) m = fmaxf(m, __shfl_xor(m, off, 64));
  if (lane == 0) redm[wave] = m;
  __syncthreads();
  float bm = redm[0];
#pragma unroll
  for (int i = 1; i < 8; ++i) bm = fmaxf(bm, redm[i]);

  float e = expf(acc - bm);
  float ss = e;
#pragma unroll
  for (int off = 32; off >= 1; off >>= 1) ss += __shfl_xor(ss, off, 64);
  if (lane == 0) reds[wave] = ss;
  __syncthreads();
  float bs = 0.f;
#pragma unroll
  for (int i = 0; i < 8; ++i) bs += reds[i];

  attn2[(size_t)bd * SS + s] = e / bs;
}

// Kernel 3: out = x, with the main diagonal scaled by attn2. float4 copy.
// One float4 = 4 consecutive columns of one row; diagonal hit iff
// row>>2 == colbase>>2 (colbase is a multiple of 4).
__global__ __launch_bounds__(256) void diag_scale_copy_kernel(
    const float4* __restrict__ xin, const float* __restrict__ attn2,
    float4* __restrict__ out) {
  const size_t v = (size_t)blockIdx.x * blockDim.x + threadIdx.x;  // float4 idx
  const size_t e = v << 2;                                         // element idx
  float4 val = xin[v];
  const int row     = (int)((e >> 9) & (SS - 1));
  const int colbase = (int)(e & (SS - 1));
  if ((row >> 2) == (colbase >> 2)) {
    const int slab = (int)(e >> 18);               // b*CC + c
    const float a = attn2[(size_t)slab * SS + row];
    switch (row & 3) {
      case 0: val.x *= a; break;
      case 1: val.y *= a; break;
      case 2: val.z *= a; break;
      default: val.w *= a; break;
    }
  }
  out[v] = val;
}

extern "C" void kernel_launch(void* const* d_in, const int* in_sizes, int n_in,
                              void* d_out, int out_size, void* d_ws, size_t ws_size,
                              hipStream_t stream) {
  const float* x       = (const float*)d_in[0];
  const float* conv_w  = (const float*)d_in[1];
  const float* point_w = (const float*)d_in[2];
  const float* point_b = (const float*)d_in[3];
  float* out = (float*)d_out;

  float* attn1 = (float*)d_ws;                       // B*C*S floats = 768 KB
  float* attn2 = attn1 + (size_t)BB * CC * SS;       // another 768 KB

  band_conv_kernel<<<BB * CC, SS, 0, stream>>>(x, conv_w, attn1);
  point_softmax_kernel<<<BB * CC, SS, 0, stream>>>(attn1, point_w, point_b, attn2);

  const size_t total4 = (size_t)BB * CC * SS * SS / 4;   // 25165824
  const int blk = 256;
  const int grid = (int)(total4 / blk);                  // 98304, exact
  diag_scale_copy_kernel<<<grid, blk, 0, stream>>>((const float4*)x, attn2,
                                                   (float4*)out);
}